// Round 2
// baseline (420.358 us; speedup 1.0000x reference)
//
#include <hip/hip_runtime.h>
#include <hip/hip_bf16.h>

// Problem: B=32, c_in=32, T=12, N=1024, ks=3, c_out=64
//   x_c[b,i,t,k,n] = sum_m Lk[k,n,m] * x[b,i,t,m]       (GEMM: 12288 x 3072 x 1024)
//   x_gc[b,o,t,n]  = sum_{i,k} theta[i,o,k]*x_c + b[o]
//   out = relu(x_gc + pad(x))

typedef __attribute__((ext_vector_type(8))) short s16x8;
typedef __attribute__((ext_vector_type(4))) float f32x4;
typedef __attribute__((ext_vector_type(4))) float fvec4;

__device__ __forceinline__ short f2bf(float f) {
    union { float f; unsigned u; } v; v.f = f;
    unsigned r = v.u + 0x7fffu + ((v.u >> 16) & 1u);   // RNE
    return (short)(r >> 16);
}
__device__ __forceinline__ float bf2f(short h) {
    union { unsigned u; float f; } v; v.u = ((unsigned)(unsigned short)h) << 16;
    return v.f;
}

// ---- fp32 -> bf16 convert, 8 elems/thread -------------------------------
__global__ __launch_bounds__(256) void cvt_bf16_k(const float* __restrict__ src,
                                                  short* __restrict__ dst, int n8) {
    int i = blockIdx.x * 256 + threadIdx.x;
    if (i >= n8) return;
    const fvec4* s4 = (const fvec4*)src;
    fvec4 a = s4[2 * i], b = s4[2 * i + 1];
    s16x8 o;
    o[0] = f2bf(a[0]); o[1] = f2bf(a[1]); o[2] = f2bf(a[2]); o[3] = f2bf(a[3]);
    o[4] = f2bf(b[0]); o[5] = f2bf(b[1]); o[6] = f2bf(b[2]); o[7] = f2bf(b[3]);
    ((s16x8*)dst)[i] = o;
}

// ---- theta (i,o,k) -> thT[o][i*3+k] -------------------------------------
__global__ __launch_bounds__(256) void tth_k(const float* __restrict__ th,
                                             float* __restrict__ thT) {
    int idx = blockIdx.x * 256 + threadIdx.x;
    if (idx >= 6144) return;
    int i = idx / 192, rem = idx % 192;
    thT[(rem / 3) * 96 + i * 3 + (rem % 3)] = th[idx];
}

// ---- bf16 MFMA GEMM, C = A * B^T; A:12288x1024, Bm(row n', col m):3072x1024
// 128x128 tile, BK=64, 4 waves (2x2), 16x16x32 MFMA, global_load_lds w=16.
__global__ __launch_bounds__(256) void gemm_bt_k(const short* __restrict__ A,
                                                 const short* __restrict__ Bm,
                                                 short* __restrict__ C) {
    __shared__ short lA[128 * 64];
    __shared__ short lB[128 * 64];
    const int tid = threadIdx.x;
    const int lane = tid & 63;
    const int w = tid >> 6;
    const int wm = w >> 1, wn = w & 1;
    const int bn = blockIdx.x, bm = blockIdx.y;
    const int arow0 = bm * 128, brow0 = bn * 128;
    const int s_row = lane >> 3;          // 0..7 row within 8-row group
    const int s_col = (lane & 7) * 8;     // bf16 col offset

    f32x4 acc[4][4] = {};

    for (int kt = 0; kt < 16; ++kt) {
        const int k0 = kt * 64;
        #pragma unroll
        for (int j = 0; j < 4; ++j) {
            const int g = w * 4 + j;      // 8-row group id, wave-uniform
            __builtin_amdgcn_global_load_lds(
                (const __attribute__((address_space(1))) void*)
                    (A + (arow0 + g * 8 + s_row) * 1024 + k0 + s_col),
                (__attribute__((address_space(3))) void*)(&lA[g * 512]), 16, 0, 0);
            __builtin_amdgcn_global_load_lds(
                (const __attribute__((address_space(1))) void*)
                    (Bm + (brow0 + g * 8 + s_row) * 1024 + k0 + s_col),
                (__attribute__((address_space(3))) void*)(&lB[g * 512]), 16, 0, 0);
        }
        __syncthreads();
        #pragma unroll
        for (int ks = 0; ks < 2; ++ks) {
            const int kf = ks * 32 + (lane >> 4) * 8;
            s16x8 af[4], bfr[4];
            #pragma unroll
            for (int mi = 0; mi < 4; ++mi)
                af[mi] = *(const s16x8*)&lA[(wm * 64 + mi * 16 + (lane & 15)) * 64 + kf];
            #pragma unroll
            for (int ni = 0; ni < 4; ++ni)
                bfr[ni] = *(const s16x8*)&lB[(wn * 64 + ni * 16 + (lane & 15)) * 64 + kf];
            #pragma unroll
            for (int mi = 0; mi < 4; ++mi)
                #pragma unroll
                for (int ni = 0; ni < 4; ++ni)
                    acc[mi][ni] = __builtin_amdgcn_mfma_f32_16x16x32_bf16(
                        af[mi], bfr[ni], acc[mi][ni], 0, 0, 0);
        }
        __syncthreads();
    }

    // C/D layout: col = lane&15, row = (lane>>4)*4 + reg  (HW-verified m89/m91)
    const int rq = (lane >> 4) * 4;
    const int cc = lane & 15;
    #pragma unroll
    for (int mi = 0; mi < 4; ++mi) {
        #pragma unroll
        for (int ni = 0; ni < 4; ++ni) {
            const int r0 = arow0 + wm * 64 + mi * 16 + rq;
            const int c  = brow0 + wn * 64 + ni * 16 + cc;
            #pragma unroll
            for (int r = 0; r < 4; ++r)
                C[(r0 + r) * 3072 + c] = f2bf(acc[mi][ni][r]);
        }
    }
}

// ---- stage 2: theta contraction + bias + residual pad + relu ------------
// xc: (b,i,t, k*1024+n) bf16; thT: [o][96] f32; out: (b,o,t,n) f32
__global__ __launch_bounds__(256) void stage2_k(const short* __restrict__ xc,
                                                const float* __restrict__ thT,
                                                const float* __restrict__ bias,
                                                const float* __restrict__ x,
                                                float* __restrict__ out) {
    const int blk = blockIdx.x;
    const int tid = threadIdx.x;
    const int nb = blk & 3;
    const int t  = (blk >> 2) % 12;
    const int b  = blk / 48;
    const int n  = nb * 256 + tid;

    float v[96];
    #pragma unroll
    for (int i = 0; i < 32; ++i) {
        const int base = ((b * 32 + i) * 12 + t) * 3072 + n;
        #pragma unroll
        for (int k = 0; k < 3; ++k)
            v[i * 3 + k] = bf2f(xc[base + k * 1024]);
    }
    const int xbase = (b * 32 * 12 + t) * 1024 + n;
    const int obase = (b * 64 * 12 + t) * 1024 + n;
    for (int o = 0; o < 64; ++o) {
        const float* th = thT + o * 96;   // wave-uniform -> s_load
        float s = bias[o];
        #pragma unroll
        for (int j = 0; j < 96; ++j) s = fmaf(th[j], v[j], s);
        if (o < 32) s += x[xbase + o * 12288];
        out[obase + o * 12288] = fmaxf(s, 0.f);
    }
}

extern "C" void kernel_launch(void* const* d_in, const int* in_sizes, int n_in,
                              void* d_out, int out_size, void* d_ws, size_t ws_size,
                              hipStream_t stream) {
    const float* x     = (const float*)d_in[0];
    const float* Lk    = (const float*)d_in[1];
    const float* theta = (const float*)d_in[2];
    const float* bias  = (const float*)d_in[3];
    float* out = (float*)d_out;

    char* ws = (char*)d_ws;
    short* xb  = (short*)(ws);                                  // 25,165,824 B
    short* lb  = (short*)(ws + 25165824);                       //  6,291,456 B
    float* thT = (float*)(ws + 25165824 + 6291456);             //     24,576 B
    short* xc  = (short*)(ws + 25165824 + 6291456 + 24576);     // 75,497,472 B
    // total ws need: 106,979,328 B

    hipLaunchKernelGGL(cvt_bf16_k, dim3(6144), dim3(256), 0, stream, x,  xb, 1572864);
    hipLaunchKernelGGL(cvt_bf16_k, dim3(1536), dim3(256), 0, stream, Lk, lb, 393216);
    hipLaunchKernelGGL(tth_k,      dim3(24),   dim3(256), 0, stream, theta, thT);
    hipLaunchKernelGGL(gemm_bt_k,  dim3(24, 96), dim3(256), 0, stream, xb, lb, xc);
    hipLaunchKernelGGL(stage2_k,   dim3(1536), dim3(256), 0, stream, xc, thT, bias, x, out);
}

// Round 3
// 326.698 us; speedup vs baseline: 1.2867x; 1.2867x over previous
//
#include <hip/hip_runtime.h>
#include <hip/hip_bf16.h>

// Problem: B=32, c_in=32, T=12, N=1024, ks=3, c_out=64
//   x_c[b,i,t,k,n] = sum_m Lk[k,n,m] * x[b,i,t,m]       (GEMM: 12288 x 3072 x 1024)
//   x_gc[b,o,t,n]  = sum_{i,k} theta[i,o,k]*x_c + b[o]
//   out = relu(x_gc + pad(x))

typedef __attribute__((ext_vector_type(8))) short s16x8;
typedef __attribute__((ext_vector_type(4))) float f32x4;
typedef __attribute__((ext_vector_type(4))) float fvec4;

__device__ __forceinline__ short f2bf(float f) {
    union { float f; unsigned u; } v; v.f = f;
    unsigned r = v.u + 0x7fffu + ((v.u >> 16) & 1u);   // RNE
    return (short)(r >> 16);
}
__device__ __forceinline__ float bf2f(short h) {
    union { unsigned u; float f; } v; v.u = ((unsigned)(unsigned short)h) << 16;
    return v.f;
}

// ---- fp32 -> bf16 convert, 8 elems/thread -------------------------------
__global__ __launch_bounds__(256) void cvt_bf16_k(const float* __restrict__ src,
                                                  short* __restrict__ dst, int n8) {
    int i = blockIdx.x * 256 + threadIdx.x;
    if (i >= n8) return;
    const fvec4* s4 = (const fvec4*)src;
    fvec4 a = s4[2 * i], b = s4[2 * i + 1];
    s16x8 o;
    o[0] = f2bf(a[0]); o[1] = f2bf(a[1]); o[2] = f2bf(a[2]); o[3] = f2bf(a[3]);
    o[4] = f2bf(b[0]); o[5] = f2bf(b[1]); o[6] = f2bf(b[2]); o[7] = f2bf(b[3]);
    ((s16x8*)dst)[i] = o;
}

// ---- theta (i,o,k) -> thT2[(i*3+k)*64 + o] ------------------------------
__global__ __launch_bounds__(256) void tth_k(const float* __restrict__ th,
                                             float* __restrict__ thT) {
    int idx = blockIdx.x * 256 + threadIdx.x;
    if (idx >= 6144) return;
    int i = idx / 192, rem = idx % 192;
    int o = rem / 3, k = rem % 3;
    thT[(i * 3 + k) * 64 + o] = th[idx];
}

// ---- bf16 MFMA GEMM, C = A * B^T; A:12288x1024, Bm(row n', col m):3072x1024
// 128x128 tile, BK=64, 4 waves (2x2), 16x16x32 MFMA, global_load_lds w=16.
__global__ __launch_bounds__(256) void gemm_bt_k(const short* __restrict__ A,
                                                 const short* __restrict__ Bm,
                                                 short* __restrict__ C) {
    __shared__ short lA[128 * 64];
    __shared__ short lB[128 * 64];
    const int tid = threadIdx.x;
    const int lane = tid & 63;
    const int w = tid >> 6;
    const int wm = w >> 1, wn = w & 1;
    const int bn = blockIdx.x, bm = blockIdx.y;
    const int arow0 = bm * 128, brow0 = bn * 128;
    const int s_row = lane >> 3;          // 0..7 row within 8-row group
    const int s_col = (lane & 7) * 8;     // bf16 col offset

    f32x4 acc[4][4] = {};

    for (int kt = 0; kt < 16; ++kt) {
        const int k0 = kt * 64;
        #pragma unroll
        for (int j = 0; j < 4; ++j) {
            const int g = w * 4 + j;      // 8-row group id, wave-uniform
            __builtin_amdgcn_global_load_lds(
                (const __attribute__((address_space(1))) void*)
                    (A + (arow0 + g * 8 + s_row) * 1024 + k0 + s_col),
                (__attribute__((address_space(3))) void*)(&lA[g * 512]), 16, 0, 0);
            __builtin_amdgcn_global_load_lds(
                (const __attribute__((address_space(1))) void*)
                    (Bm + (brow0 + g * 8 + s_row) * 1024 + k0 + s_col),
                (__attribute__((address_space(3))) void*)(&lB[g * 512]), 16, 0, 0);
        }
        __syncthreads();
        #pragma unroll
        for (int ks = 0; ks < 2; ++ks) {
            const int kf = ks * 32 + (lane >> 4) * 8;
            s16x8 af[4], bfr[4];
            #pragma unroll
            for (int mi = 0; mi < 4; ++mi)
                af[mi] = *(const s16x8*)&lA[(wm * 64 + mi * 16 + (lane & 15)) * 64 + kf];
            #pragma unroll
            for (int ni = 0; ni < 4; ++ni)
                bfr[ni] = *(const s16x8*)&lB[(wn * 64 + ni * 16 + (lane & 15)) * 64 + kf];
            #pragma unroll
            for (int mi = 0; mi < 4; ++mi)
                #pragma unroll
                for (int ni = 0; ni < 4; ++ni)
                    acc[mi][ni] = __builtin_amdgcn_mfma_f32_16x16x32_bf16(
                        af[mi], bfr[ni], acc[mi][ni], 0, 0, 0);
        }
        __syncthreads();
    }

    // C/D layout: col = lane&15, row = (lane>>4)*4 + reg  (HW-verified m89/m91)
    const int rq = (lane >> 4) * 4;
    const int cc = lane & 15;
    #pragma unroll
    for (int mi = 0; mi < 4; ++mi) {
        #pragma unroll
        for (int ni = 0; ni < 4; ++ni) {
            const int r0 = arow0 + wm * 64 + mi * 16 + rq;
            const int c  = brow0 + wn * 64 + ni * 16 + cc;
            #pragma unroll
            for (int r = 0; r < 4; ++r)
                C[(r0 + r) * 3072 + c] = f2bf(acc[mi][ni][r]);
        }
    }
}

// ---- stage 2: theta contraction + bias + residual pad + relu ------------
// xc: (b,i,t, k*1024+n) bf16; thT2: [ik=96][o=64] f32; out: (b,o,t,n) f32
// Accumulator-major structure: per-thread acc[64] (registers, static idx),
// stream over ik. theta rows are wave-uniform -> scalar loads.
__global__ __launch_bounds__(256) void stage2_k(const short* __restrict__ xc,
                                                const float* __restrict__ thT,
                                                const float* __restrict__ bias,
                                                const float* __restrict__ x,
                                                float* __restrict__ out) {
    const int blk = blockIdx.x;
    const int tid = threadIdx.x;
    const int nb = blk & 3;
    const int bt = blk >> 2;          // b*12 + t
    const int b  = bt / 12;
    const int t  = bt - b * 12;
    const int n  = nb * 256 + tid;

    float acc[64];
    #pragma unroll
    for (int o = 0; o < 64; ++o) acc[o] = 0.f;

    const int xcbase = (b * 384 + t) * 3072 + n;   // i = 0, k = 0
    for (int i = 0; i < 32; ++i) {
        const int base = xcbase + i * 36864;
        const float v0 = bf2f(xc[base]);
        const float v1 = bf2f(xc[base + 1024]);
        const float v2 = bf2f(xc[base + 2048]);
        const float* t0 = thT + (i * 3) * 64;      // wave-uniform
        #pragma unroll
        for (int o = 0; o < 64; ++o)
            acc[o] = fmaf(t0[o], v0,
                     fmaf(t0[64 + o], v1,
                     fmaf(t0[128 + o], v2, acc[o])));
    }

    const int xrbase = (b * 384 + t) * 1024 + n;   // residual, i = o
    const int obase  = (b * 768 + t) * 1024 + n;
    #pragma unroll
    for (int o = 0; o < 64; ++o) {
        float s = acc[o] + bias[o];
        if (o < 32) s += x[xrbase + o * 12288];
        out[obase + o * 12288] = fmaxf(s, 0.f);
    }
}

extern "C" void kernel_launch(void* const* d_in, const int* in_sizes, int n_in,
                              void* d_out, int out_size, void* d_ws, size_t ws_size,
                              hipStream_t stream) {
    const float* x     = (const float*)d_in[0];
    const float* Lk    = (const float*)d_in[1];
    const float* theta = (const float*)d_in[2];
    const float* bias  = (const float*)d_in[3];
    float* out = (float*)d_out;

    char* ws = (char*)d_ws;
    short* xb  = (short*)(ws);                                  // 25,165,824 B
    short* lb  = (short*)(ws + 25165824);                       //  6,291,456 B
    float* thT = (float*)(ws + 25165824 + 6291456);             //     24,576 B
    short* xc  = (short*)(ws + 25165824 + 6291456 + 24576);     // 75,497,472 B
    // total ws need: 106,979,328 B

    hipLaunchKernelGGL(cvt_bf16_k, dim3(6144), dim3(256), 0, stream, x,  xb, 1572864);
    hipLaunchKernelGGL(cvt_bf16_k, dim3(1536), dim3(256), 0, stream, Lk, lb, 393216);
    hipLaunchKernelGGL(tth_k,      dim3(24),   dim3(256), 0, stream, theta, thT);
    hipLaunchKernelGGL(gemm_bt_k,  dim3(24, 96), dim3(256), 0, stream, xb, lb, xc);
    hipLaunchKernelGGL(stage2_k,   dim3(1536), dim3(256), 0, stream, xc, thT, bias, x, out);
}